// Round 2
// baseline (757.228 us; speedup 1.0000x reference)
//
#include <hip/hip_runtime.h>

#define VV 10000
#define EE 128
#define NROWS 2048   // B*C
#define KS 32        // K3 split-K factor

typedef unsigned short u16;
using short8 = __attribute__((ext_vector_type(8))) short;
using f32x4  = __attribute__((ext_vector_type(4))) float;

// round-to-nearest-even f32 -> bf16 bits
__device__ __forceinline__ u16 f2bf(float x) {
    unsigned u = __float_as_uint(x);
    return (u16)((u + 0x7fffu + ((u >> 16) & 1u)) >> 16);
}
__device__ __forceinline__ float bf2f(u16 h) {
    return __uint_as_float(((unsigned)h) << 16);
}

// ---------------------------------------------------------------------------
// K0: build fragment-major bf16 hi/lo operand planes.
//   SEh/SEl : [128 nf][4 kt][64 lane][8]   from SE[2048][128]   (A of K1)
//   Wh/Wl   : [625 vf][4 kt][64 lane][8]   from W[10000][128]   (B of K1, NT)
//   WTh/WTl : [8 ef][313 kc][64 lane][8]   from W^T (B of K3), k-padded to 10016
// ---------------------------------------------------------------------------
__global__ __launch_bounds__(256) void k0_prep(
    const float* __restrict__ SE,   // [2048][128]
    const float* __restrict__ W,    // [10000][128]
    u16* __restrict__ SEh, u16* __restrict__ SEl,
    u16* __restrict__ Wh,  u16* __restrict__ Wl,
    u16* __restrict__ WTh, u16* __restrict__ WTl)
{
    const int u = blockIdx.x * 256 + threadIdx.x;
    float x[8];
    u16 *dh, *dl;

    if (u < 32768) {                       // SE planes
        int fid = u >> 6, l = u & 63;
        int nf = fid >> 2, kt = fid & 3;
        int row = nf * 16 + (l & 15);
        int k0 = kt * 32 + (l >> 4) * 8;
        const float* p = SE + row * EE + k0;
        float4 a = *(const float4*)p, b = *(const float4*)(p + 4);
        x[0]=a.x; x[1]=a.y; x[2]=a.z; x[3]=a.w;
        x[4]=b.x; x[5]=b.y; x[6]=b.z; x[7]=b.w;
        dh = SEh + u * 8; dl = SEl + u * 8;
    } else if (u < 192768) {               // W planes (row-major, K1 B-operand)
        int u2 = u - 32768;
        int fid = u2 >> 6, l = u2 & 63;
        int vf = fid >> 2, kt = fid & 3;
        int row = vf * 16 + (l & 15);      // vf<=624 -> row<=9999
        int k0 = kt * 32 + (l >> 4) * 8;
        const float* p = W + row * EE + k0;
        float4 a = *(const float4*)p, b = *(const float4*)(p + 4);
        x[0]=a.x; x[1]=a.y; x[2]=a.z; x[3]=a.w;
        x[4]=b.x; x[5]=b.y; x[6]=b.z; x[7]=b.w;
        dh = Wh + u2 * 8; dl = Wl + u2 * 8;
    } else {                               // W^T planes (K3 B-operand), k-padded
        int u3 = u - 192768;
        int fid = u3 >> 6, l = u3 & 63;
        int ef = fid / 313, kc = fid - ef * 313;
        int e  = ef * 16 + (l & 15);
        int k8 = kc * 32 + (l >> 4) * 8;
        if (k8 < VV) {
            #pragma unroll
            for (int i = 0; i < 8; i++) x[i] = W[(k8 + i) * EE + e];
        } else {
            #pragma unroll
            for (int i = 0; i < 8; i++) x[i] = 0.f;
        }
        dh = WTh + u3 * 8; dl = WTl + u3 * 8;
    }

    short8 hv, lv;
    #pragma unroll
    for (int i = 0; i < 8; i++) {
        u16 hb = f2bf(x[i]);
        hv[i] = (short)hb;
        lv[i] = (short)f2bf(x[i] - bf2f(hb));
    }
    *(short8*)dh = hv;
    *(short8*)dl = lv;
}

// ---------------------------------------------------------------------------
// K1: base[n][v] = dot(SE[n][:], W[v][:]) via bf16 hi/lo 3-MFMA split.
// Block 256 thr = 4 waves (2n x 2v); block tile 64n x 128v; wave 32n x 64v.
// grid (32 nt, 79 vt): x-major dispatch -> consecutive blocks share the same
// W-plane slice (64 KB) for XCD-L2 reuse.
// ---------------------------------------------------------------------------
__global__ __launch_bounds__(256) void k1_mfma(
    const u16* __restrict__ SEh, const u16* __restrict__ SEl,
    const u16* __restrict__ Wh,  const u16* __restrict__ Wl,
    float* __restrict__ base)
{
    const int tid = threadIdx.x;
    const int l = tid & 63, wv = tid >> 6;
    const int wn = wv >> 1, wq = wv & 1;
    const int vt = blockIdx.y, nt = blockIdx.x;
    const int nf0 = nt * 4 + wn * 2;   // 2 n-frags
    const int vf0 = vt * 8 + wq * 4;   // 4 v-frags

    f32x4 acc[2][4];
    #pragma unroll
    for (int i = 0; i < 2; i++)
        #pragma unroll
        for (int j = 0; j < 4; j++)
            acc[i][j] = (f32x4){0.f, 0.f, 0.f, 0.f};

    #pragma unroll
    for (int kt = 0; kt < 4; ++kt) {
        short8 ah[2], al[2];
        #pragma unroll
        for (int i = 0; i < 2; ++i) {
            int off = (((nf0 + i) * 4 + kt) * 64 + l) * 8;
            ah[i] = *(const short8*)(SEh + off);
            al[i] = *(const short8*)(SEl + off);
        }
        #pragma unroll
        for (int j = 0; j < 4; ++j) {
            int vf = vf0 + j;
            short8 bh = {0,0,0,0,0,0,0,0};
            short8 bl = {0,0,0,0,0,0,0,0};
            if (vf < 625) {
                int off = ((vf * 4 + kt) * 64 + l) * 8;
                bh = *(const short8*)(Wh + off);
                bl = *(const short8*)(Wl + off);
            }
            #pragma unroll
            for (int i = 0; i < 2; ++i) {
                acc[i][j] = __builtin_amdgcn_mfma_f32_16x16x32_bf16(ah[i], bh, acc[i][j], 0, 0, 0);
                acc[i][j] = __builtin_amdgcn_mfma_f32_16x16x32_bf16(ah[i], bl, acc[i][j], 0, 0, 0);
                acc[i][j] = __builtin_amdgcn_mfma_f32_16x16x32_bf16(al[i], bh, acc[i][j], 0, 0, 0);
            }
        }
    }

    // D layout: col = lane&15, row = (lane>>4)*4 + reg   [m89-verified]
    const int c = l & 15, r0 = (l >> 4) * 4;
    #pragma unroll
    for (int j = 0; j < 4; ++j) {
        int vf = vf0 + j;
        if (vf >= 625) continue;
        int v = vf * 16 + c;
        #pragma unroll
        for (int i = 0; i < 2; ++i) {
            int n = (nf0 + i) * 16 + r0;
            #pragma unroll
            for (int r = 0; r < 4; ++r)
                base[(n + r) * VV + v] = acc[i][j][r];
        }
    }
}

// ---------------------------------------------------------------------------
// K2: per row n: gather rel/edge rows + base row, per-relation softmax stats,
// relation softmax, rewrite base row in place as A[v].
// This version: seb/srb live in REGISTERS (fully unrolled 10-iter grid-stride,
// 40 f32 + 10 packed u32 per thread) instead of 50 KB LDS -> occupancy no
// longer LDS-capped, no LDS BW on the 40 KB seb array.  Math identical.
// ---------------------------------------------------------------------------
__global__ __launch_bounds__(256, 4) void k2_stats(
    const int*   __restrict__ src,
    const float* __restrict__ edge,    // [V][V]
    const int*   __restrict__ rel,     // [V][V]
    float* __restrict__ baseA)         // [2048][10000] in/out
{
    __shared__ float wred[33][4];
    __shared__ float fin[33];
    __shared__ float cvals[12];            // [0]=0, [1..8]=c_q, [9]=Kc

    const int n = blockIdx.x;
    const int tid = threadIdx.x;
    const int lane = tid & 63;
    const int wv = tid >> 6;
    const int s = src[n];
    const float4* brow4 = (const float4*)(baseA + (long long)n * VV);
    const float4* erow4 = (const float4*)(edge + (long long)s * VV);
    const int4*   rrow4 = (const int4*)(rel + (long long)s * VV);

    float accv[33];
    #pragma unroll
    for (int i = 0; i < 33; i++) accv[i] = 0.f;

    float    ebr[10][4];    // exp(base) per handled element (register file)
    unsigned srp[10];       // 4x relation codes packed per iteration

    #pragma unroll
    for (int it = 0; it < 10; ++it) {
        int v4 = tid + it * 256;
        unsigned pk = 0u;
        if (v4 < VV / 4) {
            float4 b = brow4[v4];
            float4 e = erow4[v4];
            int4   r = rrow4[v4];
            float bb[4] = {b.x, b.y, b.z, b.w};
            float ee[4] = {e.x, e.y, e.z, e.w};
            int   rr[4] = {r.x, r.y, r.z, r.w};
            #pragma unroll
            for (int c = 0; c < 4; c++) {
                int rb = (rr[c] >= 1 && rr[c] <= 8 && ee[c] > 0.f) ? rr[c] : 0;
                float bc = bb[c];
                float eb = __expf(bc);
                float beb = bc * eb;
                ebr[it][c] = eb;
                pk |= ((unsigned)rb) << (8 * c);
                accv[0] += bc;
                #pragma unroll
                for (int q = 0; q < 8; q++) {
                    float m = (rb == q + 1) ? 1.f : 0.f;
                    accv[1 + q]  += m;
                    accv[9 + q]  = fmaf(m, bc,  accv[9 + q]);
                    accv[17 + q] = fmaf(m, eb,  accv[17 + q]);
                    accv[25 + q] = fmaf(m, beb, accv[25 + q]);
                }
            }
        } else {
            #pragma unroll
            for (int c = 0; c < 4; c++) ebr[it][c] = 1.f;
        }
        srp[it] = pk;
    }

    #pragma unroll
    for (int i = 0; i < 33; i++) {
        float x = accv[i];
        #pragma unroll
        for (int off = 32; off > 0; off >>= 1) x += __shfl_xor(x, off, 64);
        if (lane == 0) wred[i][wv] = x;
    }
    __syncthreads();
    if (tid < 33)
        fin[tid] = wred[tid][0] + wred[tid][1] + wred[tid][2] + wred[tid][3];
    __syncthreads();

    if (tid == 0) {
        float sumbase = fin[0];
        float sc[8], Z[8];
        float smax = -1e30f;
        #pragma unroll
        for (int q = 0; q < 8; q++) {
            Z[q]  = ((float)VV - fin[1 + q]) + fin[17 + q];
            sc[q] = (sumbase - fin[9 + q] + fin[25 + q]) / Z[q];
            smax = fmaxf(smax, sc[q]);
        }
        float wsum = 0.f, wq[8];
        #pragma unroll
        for (int q = 0; q < 8; q++) { wq[q] = __expf(sc[q] - smax); wsum += wq[q]; }
        float Kc = 0.f;
        #pragma unroll
        for (int q = 0; q < 8; q++) {
            float c = (wq[q] / wsum) / Z[q];
            cvals[1 + q] = c;
            Kc += c;
        }
        cvals[0] = 0.f;
        cvals[9] = Kc;
    }
    __syncthreads();

    const float Kc = cvals[9];
    float4* broww = (float4*)(baseA + (long long)n * VV);
    #pragma unroll
    for (int it = 0; it < 10; ++it) {
        int v4 = tid + it * 256;
        if (v4 < VV / 4) {
            unsigned pk = srp[it];
            float o[4];
            #pragma unroll
            for (int c = 0; c < 4; c++) {
                float eb = ebr[it][c];
                float cc = cvals[(pk >> (8 * c)) & 255u];   // 0 for unmasked
                o[c] = fmaf(cc, eb - 1.f, Kc);
            }
            broww[v4] = make_float4(o[0], o[1], o[2], o[3]);
        }
    }
}

// ---------------------------------------------------------------------------
// K3: part[ks][m][e] = sum_{kc in split ks} A[m][k] * W[k][e], bf16 3-MFMA.
// Retiled for occupancy: wave = 16m x 128e (1 m-frag), grid (32 mt, 32 ks)
// = 1024 blocks = 4 blocks/CU = 16 waves/CU (was 2 waves/SIMD).
// Contiguous-k split: block's ~10 kc are sequential (DRAM streaming) and
// consecutive blocks share the same ks -> same 160 KB WT slice in XCD L2.
// ---------------------------------------------------------------------------
__global__ __launch_bounds__(256) void k3_mfma(
    const float* __restrict__ A,      // [2048][10000]
    const u16* __restrict__ WTh, const u16* __restrict__ WTl,
    float* __restrict__ part)         // [32][2048][128]
{
    const int tid = threadIdx.x;
    const int l = tid & 63, wv = tid >> 6;
    const int mt = blockIdx.x, ks = blockIdx.y;
    const int mf = mt * 4 + wv;        // 1 m-frag per wave, 128 total
    const int g = l >> 4, rr_ = l & 15;
    const int kc0 = (313 * ks) / KS;
    const int kc1 = (313 * (ks + 1)) / KS;

    f32x4 acc[8];
    #pragma unroll
    for (int j = 0; j < 8; j++) acc[j] = (f32x4){0.f, 0.f, 0.f, 0.f};

    const float* arow = A + (long long)(mf * 16 + rr_) * VV;

    #pragma unroll 2
    for (int kc = kc0; kc < kc1; ++kc) {
        int k8 = kc * 32 + g * 8;
        short8 ah, al;
        {
            float x[8];
            if (k8 < VV) {                      // octet fully in or fully out
                const float* p = arow + k8;
                float4 a = *(const float4*)p, b = *(const float4*)(p + 4);
                x[0]=a.x; x[1]=a.y; x[2]=a.z; x[3]=a.w;
                x[4]=b.x; x[5]=b.y; x[6]=b.z; x[7]=b.w;
            } else {
                #pragma unroll
                for (int q = 0; q < 8; q++) x[q] = 0.f;
            }
            #pragma unroll
            for (int q = 0; q < 8; q++) {
                u16 hb = f2bf(x[q]);
                ah[q] = (short)hb;
                al[q] = (short)f2bf(x[q] - bf2f(hb));
            }
        }
        #pragma unroll
        for (int j = 0; j < 8; ++j) {
            int off = ((j * 313 + kc) * 64 + l) * 8;
            short8 bh = *(const short8*)(WTh + off);
            short8 bl = *(const short8*)(WTl + off);
            acc[j] = __builtin_amdgcn_mfma_f32_16x16x32_bf16(ah, bh, acc[j], 0, 0, 0);
            acc[j] = __builtin_amdgcn_mfma_f32_16x16x32_bf16(ah, bl, acc[j], 0, 0, 0);
            acc[j] = __builtin_amdgcn_mfma_f32_16x16x32_bf16(al, bh, acc[j], 0, 0, 0);
        }
    }

    float* pp = part + (long long)ks * NROWS * EE;
    const int c = l & 15, r0 = g * 4;
    #pragma unroll
    for (int j = 0; j < 8; ++j) {
        int e = j * 16 + c;
        int m = mf * 16 + r0;
        #pragma unroll
        for (int r = 0; r < 4; ++r)
            pp[(m + r) * EE + e] = acc[j][r];
    }
}

// ---------------------------------------------------------------------------
// K4: out = sum over 32 splits of partial.  65536 float4 elements.
// ---------------------------------------------------------------------------
__global__ __launch_bounds__(256) void k4_reduce(
    const float* __restrict__ part, float* __restrict__ out)
{
    int idx = blockIdx.x * 256 + threadIdx.x;       // float4 index
    const float4* p = (const float4*)part;
    const int stride = NROWS * EE / 4;              // 65536
    float4 s = p[idx];
    #pragma unroll
    for (int k = 1; k < KS; k++) {
        float4 t = p[idx + k * stride];
        s.x += t.x; s.y += t.y; s.z += t.z; s.w += t.w;
    }
    ((float4*)out)[idx] = s;
}

extern "C" void kernel_launch(void* const* d_in, const int* in_sizes, int n_in,
                              void* d_out, int out_size, void* d_ws, size_t ws_size,
                              hipStream_t stream) {
    const int*   src  = (const int*)  d_in[0];
    const float* SE   = (const float*)d_in[1];
    const float* W    = (const float*)d_in[2];
    const float* edge = (const float*)d_in[3];
    const int*   rel  = (const int*)  d_in[4];
    float* out  = (float*)d_out;

    float* base = (float*)d_ws;                      // 2048*10000 f32 = 78.1 MiB
    float* part = base + (long long)NROWS * VV;      // 32*2048*128 f32 = 32 MiB
    u16* SEh = (u16*)(part + (long long)KS * NROWS * EE);
    u16* SEl = SEh + 262144;                         // 2048*128
    u16* Wh  = SEl + 262144;
    u16* Wl  = Wh  + 1280000;                        // 10000*128
    u16* WTh = Wl  + 1280000;
    u16* WTl = WTh + 1282048;                        // 8*313*512 (k-padded)

    k0_prep<<<dim3(1379), 256, 0, stream>>>(SE, W, SEh, SEl, Wh, Wl, WTh, WTl);
    k1_mfma<<<dim3(32, 79), 256, 0, stream>>>(SEh, SEl, Wh, Wl, base);
    k2_stats<<<dim3(NROWS), 256, 0, stream>>>(src, edge, rel, base);
    k3_mfma<<<dim3(32, KS), 256, 0, stream>>>(base, WTh, WTl, part);
    k4_reduce<<<dim3(256), 256, 0, stream>>>(part, out);
}

// Round 3
// 715.080 us; speedup vs baseline: 1.0589x; 1.0589x over previous
//
#include <hip/hip_runtime.h>

#define VV 10000
#define EE 128
#define NROWS 2048   // B*C
#define KS 32        // K3 split-K factor
#define RBSTRIDE 5120  // bytes per packed rel-code row (VV/2=5000, padded)

typedef unsigned short u16;
using short8 = __attribute__((ext_vector_type(8))) short;
using f32x4  = __attribute__((ext_vector_type(4))) float;

// round-to-nearest-even f32 -> bf16 bits
__device__ __forceinline__ u16 f2bf(float x) {
    unsigned u = __float_as_uint(x);
    return (u16)((u + 0x7fffu + ((u >> 16) & 1u)) >> 16);
}
__device__ __forceinline__ float bf2f(u16 h) {
    return __uint_as_float(((unsigned)h) << 16);
}

// ---------------------------------------------------------------------------
// K0: build fragment-major bf16 hi/lo operand planes.
//   SEh/SEl : [128 nf][4 kt][64 lane][8]   from SE[2048][128]   (A of K1)
//   Wh/Wl   : [625 vf][4 kt][64 lane][8]   from W[10000][128]   (B of K1, NT)
//   WTh/WTl : [8 ef][313 kc][64 lane][8]   from W^T (B of K3), k-padded to 10016
// ---------------------------------------------------------------------------
__global__ __launch_bounds__(256) void k0_prep(
    const float* __restrict__ SE,   // [2048][128]
    const float* __restrict__ W,    // [10000][128]
    u16* __restrict__ SEh, u16* __restrict__ SEl,
    u16* __restrict__ Wh,  u16* __restrict__ Wl,
    u16* __restrict__ WTh, u16* __restrict__ WTl)
{
    const int u = blockIdx.x * 256 + threadIdx.x;
    float x[8];
    u16 *dh, *dl;

    if (u < 32768) {                       // SE planes
        int fid = u >> 6, l = u & 63;
        int nf = fid >> 2, kt = fid & 3;
        int row = nf * 16 + (l & 15);
        int k0 = kt * 32 + (l >> 4) * 8;
        const float* p = SE + row * EE + k0;
        float4 a = *(const float4*)p, b = *(const float4*)(p + 4);
        x[0]=a.x; x[1]=a.y; x[2]=a.z; x[3]=a.w;
        x[4]=b.x; x[5]=b.y; x[6]=b.z; x[7]=b.w;
        dh = SEh + u * 8; dl = SEl + u * 8;
    } else if (u < 192768) {               // W planes (row-major, K1 B-operand)
        int u2 = u - 32768;
        int fid = u2 >> 6, l = u2 & 63;
        int vf = fid >> 2, kt = fid & 3;
        int row = vf * 16 + (l & 15);      // vf<=624 -> row<=9999
        int k0 = kt * 32 + (l >> 4) * 8;
        const float* p = W + row * EE + k0;
        float4 a = *(const float4*)p, b = *(const float4*)(p + 4);
        x[0]=a.x; x[1]=a.y; x[2]=a.z; x[3]=a.w;
        x[4]=b.x; x[5]=b.y; x[6]=b.z; x[7]=b.w;
        dh = Wh + u2 * 8; dl = Wl + u2 * 8;
    } else {                               // W^T planes (K3 B-operand), k-padded
        int u3 = u - 192768;
        int fid = u3 >> 6, l = u3 & 63;
        int ef = fid / 313, kc = fid - ef * 313;
        int e  = ef * 16 + (l & 15);
        int k8 = kc * 32 + (l >> 4) * 8;
        if (k8 < VV) {
            #pragma unroll
            for (int i = 0; i < 8; i++) x[i] = W[(k8 + i) * EE + e];
        } else {
            #pragma unroll
            for (int i = 0; i < 8; i++) x[i] = 0.f;
        }
        dh = WTh + u3 * 8; dl = WTl + u3 * 8;
    }

    short8 hv, lv;
    #pragma unroll
    for (int i = 0; i < 8; i++) {
        u16 hb = f2bf(x[i]);
        hv[i] = (short)hb;
        lv[i] = (short)f2bf(x[i] - bf2f(hb));
    }
    *(short8*)dh = hv;
    *(short8*)dl = lv;
}

// ---------------------------------------------------------------------------
// K1: base[n][v] = dot(SE[n][:], W[v][:]) via bf16 hi/lo 3-MFMA split.
// Block 256 thr = 4 waves (2n x 2v); block tile 64n x 128v; wave 32n x 64v.
// grid (32 nt, 79 vt): x-major dispatch -> consecutive blocks share the same
// W-plane slice for XCD-L2 reuse.
// ---------------------------------------------------------------------------
__global__ __launch_bounds__(256) void k1_mfma(
    const u16* __restrict__ SEh, const u16* __restrict__ SEl,
    const u16* __restrict__ Wh,  const u16* __restrict__ Wl,
    float* __restrict__ base)
{
    const int tid = threadIdx.x;
    const int l = tid & 63, wv = tid >> 6;
    const int wn = wv >> 1, wq = wv & 1;
    const int vt = blockIdx.y, nt = blockIdx.x;
    const int nf0 = nt * 4 + wn * 2;   // 2 n-frags
    const int vf0 = vt * 8 + wq * 4;   // 4 v-frags

    f32x4 acc[2][4];
    #pragma unroll
    for (int i = 0; i < 2; i++)
        #pragma unroll
        for (int j = 0; j < 4; j++)
            acc[i][j] = (f32x4){0.f, 0.f, 0.f, 0.f};

    #pragma unroll
    for (int kt = 0; kt < 4; ++kt) {
        short8 ah[2], al[2];
        #pragma unroll
        for (int i = 0; i < 2; ++i) {
            int off = (((nf0 + i) * 4 + kt) * 64 + l) * 8;
            ah[i] = *(const short8*)(SEh + off);
            al[i] = *(const short8*)(SEl + off);
        }
        #pragma unroll
        for (int j = 0; j < 4; ++j) {
            int vf = vf0 + j;
            short8 bh = {0,0,0,0,0,0,0,0};
            short8 bl = {0,0,0,0,0,0,0,0};
            if (vf < 625) {
                int off = ((vf * 4 + kt) * 64 + l) * 8;
                bh = *(const short8*)(Wh + off);
                bl = *(const short8*)(Wl + off);
            }
            #pragma unroll
            for (int i = 0; i < 2; ++i) {
                acc[i][j] = __builtin_amdgcn_mfma_f32_16x16x32_bf16(ah[i], bh, acc[i][j], 0, 0, 0);
                acc[i][j] = __builtin_amdgcn_mfma_f32_16x16x32_bf16(ah[i], bl, acc[i][j], 0, 0, 0);
                acc[i][j] = __builtin_amdgcn_mfma_f32_16x16x32_bf16(al[i], bh, acc[i][j], 0, 0, 0);
            }
        }
    }

    // D layout: col = lane&15, row = (lane>>4)*4 + reg   [m89-verified]
    const int c = l & 15, r0 = (l >> 4) * 4;
    #pragma unroll
    for (int j = 0; j < 4; ++j) {
        int vf = vf0 + j;
        if (vf >= 625) continue;
        int v = vf * 16 + c;
        #pragma unroll
        for (int i = 0; i < 2; ++i) {
            int n = (nf0 + i) * 16 + r0;
            #pragma unroll
            for (int r = 0; r < 4; ++r)
                base[(n + r) * VV + v] = acc[i][j][r];
        }
    }
}

// ---------------------------------------------------------------------------
// K2: single-pass per-row stats.  Reads base (raw scores) + gathered edge/rel
// rows; emits (a) packed 4-bit relation codes rb4[n][v] and (b) per-row
// coefficients cG[n][10] = {c_0=0, c_1..c_8, Kc}.  Does NOT rewrite base --
// the softmax transform is fused into K3.  No big register arrays.
// ---------------------------------------------------------------------------
__global__ __launch_bounds__(256) void k2_stats(
    const int*   __restrict__ src,
    const float* __restrict__ edge,    // [V][V]
    const int*   __restrict__ rel,     // [V][V]
    const float* __restrict__ baseA,   // [2048][10000] (read-only)
    unsigned char* __restrict__ rb4,   // [2048][RBSTRIDE] packed 4-bit codes
    float* __restrict__ cG)            // [2048][10]
{
    __shared__ float wred[33][4];
    __shared__ float fin[33];

    const int n = blockIdx.x;
    const int tid = threadIdx.x;
    const int lane = tid & 63;
    const int wv = tid >> 6;
    const int s = src[n];
    const float4* brow4 = (const float4*)(baseA + (long long)n * VV);
    const float4* erow4 = (const float4*)(edge + (long long)s * VV);
    const int4*   rrow4 = (const int4*)(rel + (long long)s * VV);
    unsigned short* crow = (unsigned short*)(rb4 + (long long)n * RBSTRIDE);

    float accv[33];
    #pragma unroll
    for (int i = 0; i < 33; i++) accv[i] = 0.f;

    for (int v4 = tid; v4 < VV / 4; v4 += 256) {
        float4 b = brow4[v4];
        float4 e = erow4[v4];
        int4   r = rrow4[v4];
        float bb[4] = {b.x, b.y, b.z, b.w};
        float ee[4] = {e.x, e.y, e.z, e.w};
        int   rr[4] = {r.x, r.y, r.z, r.w};
        unsigned pk = 0u;
        #pragma unroll
        for (int c = 0; c < 4; c++) {
            int rb = (rr[c] >= 1 && rr[c] <= 8 && ee[c] > 0.f) ? rr[c] : 0;
            float bc = bb[c];
            float eb = __expf(bc);
            float beb = bc * eb;
            pk |= ((unsigned)rb) << (4 * c);
            accv[0] += bc;
            #pragma unroll
            for (int q = 0; q < 8; q++) {
                float m = (rb == q + 1) ? 1.f : 0.f;
                accv[1 + q]  += m;
                accv[9 + q]  = fmaf(m, bc,  accv[9 + q]);
                accv[17 + q] = fmaf(m, eb,  accv[17 + q]);
                accv[25 + q] = fmaf(m, beb, accv[25 + q]);
            }
        }
        crow[v4] = (unsigned short)pk;
    }

    #pragma unroll
    for (int i = 0; i < 33; i++) {
        float x = accv[i];
        #pragma unroll
        for (int off = 32; off > 0; off >>= 1) x += __shfl_xor(x, off, 64);
        if (lane == 0) wred[i][wv] = x;
    }
    __syncthreads();
    if (tid < 33)
        fin[tid] = wred[tid][0] + wred[tid][1] + wred[tid][2] + wred[tid][3];
    __syncthreads();

    if (tid == 0) {
        float sumbase = fin[0];
        float sc[8], Z[8];
        float smax = -1e30f;
        #pragma unroll
        for (int q = 0; q < 8; q++) {
            Z[q]  = ((float)VV - fin[1 + q]) + fin[17 + q];
            sc[q] = (sumbase - fin[9 + q] + fin[25 + q]) / Z[q];
            smax = fmaxf(smax, sc[q]);
        }
        float wsum = 0.f, wq[8];
        #pragma unroll
        for (int q = 0; q < 8; q++) { wq[q] = __expf(sc[q] - smax); wsum += wq[q]; }
        float Kc = 0.f;
        float* cg = cG + n * 10;
        #pragma unroll
        for (int q = 0; q < 8; q++) {
            float c = (wq[q] / wsum) / Z[q];
            cg[1 + q] = c;
            Kc += c;
        }
        cg[0] = 0.f;
        cg[9] = Kc;
    }
}

// ---------------------------------------------------------------------------
// K3: part[ks][m][e] = sum_k A[m][k] * W[k][e], where A is computed ON THE FLY
// from raw base scores: A = fma(c_rb, exp(b)-1, Kc)  (identical formula/bits
// to the old K2 rewrite).  bf16 hi/lo 3-MFMA.
// Block 256 thr = 4 waves as 2(m) x 2(e); wave = 32m x 64e.
// grid (32 mt, 32 ks); contiguous-k split; WT slice L2-shared along x.
// ---------------------------------------------------------------------------
__global__ __launch_bounds__(256) void k3_mfma(
    const float* __restrict__ baseA,            // [2048][10000]
    const unsigned char* __restrict__ rb4,      // [2048][RBSTRIDE]
    const float* __restrict__ cG,               // [2048][10]
    const u16* __restrict__ WTh, const u16* __restrict__ WTl,
    float* __restrict__ part)                   // [32][2048][128]
{
    __shared__ float cvt[64][10];               // per-block row coefficients

    const int tid = threadIdx.x;
    const int l = tid & 63, wv = tid >> 6;
    const int wm = wv >> 1, we = wv & 1;
    const int mt = blockIdx.x, ks = blockIdx.y;
    const int g = l >> 4, rr_ = l & 15;
    const int kc0 = (313 * ks) / KS;
    const int kc1 = (313 * (ks + 1)) / KS;

    for (int t = tid; t < 640; t += 256)
        cvt[t / 10][t % 10] = cG[(mt * 64 + t / 10) * 10 + (t % 10)];
    __syncthreads();

    const int mf0 = mt * 4 + wm * 2;            // 2 m-frags for this wave
    const int rl0 = (wm * 2) * 16 + rr_;        // local row indices into cvt
    const int rl1 = (wm * 2 + 1) * 16 + rr_;
    const float* arow0 = baseA + (long long)(mf0 * 16 + rr_) * VV;
    const float* arow1 = baseA + (long long)((mf0 + 1) * 16 + rr_) * VV;
    const unsigned char* rrow0 = rb4 + (long long)(mf0 * 16 + rr_) * RBSTRIDE;
    const unsigned char* rrow1 = rb4 + (long long)((mf0 + 1) * 16 + rr_) * RBSTRIDE;
    const float Kc0 = cvt[rl0][9];
    const float Kc1 = cvt[rl1][9];

    f32x4 acc[2][4];
    #pragma unroll
    for (int i = 0; i < 2; i++)
        #pragma unroll
        for (int j = 0; j < 4; j++)
            acc[i][j] = (f32x4){0.f, 0.f, 0.f, 0.f};

    for (int kc = kc0; kc < kc1; ++kc) {
        int k8 = kc * 32 + g * 8;
        short8 ah[2], al[2];

        #pragma unroll
        for (int i = 0; i < 2; ++i) {
            const float* arow = i ? arow1 : arow0;
            const unsigned char* rrow = i ? rrow1 : rrow0;
            const float Kci = i ? Kc1 : Kc0;
            const int rli = i ? rl1 : rl0;
            float x[8];
            if (k8 < VV) {                      // octet fully in or fully out
                float4 a = *(const float4*)(arow + k8);
                float4 b = *(const float4*)(arow + k8 + 4);
                unsigned cw = *(const unsigned*)(rrow + (k8 >> 1));
                float t[8] = {a.x, a.y, a.z, a.w, b.x, b.y, b.z, b.w};
                #pragma unroll
                for (int q = 0; q < 8; q++) {
                    float cc = cvt[rli][(cw >> (4 * q)) & 15u];  // 0 if unmasked
                    x[q] = fmaf(cc, __expf(t[q]) - 1.f, Kci);
                }
            } else {
                #pragma unroll
                for (int q = 0; q < 8; q++) x[q] = 0.f;
            }
            #pragma unroll
            for (int q = 0; q < 8; q++) {
                u16 hb = f2bf(x[q]);
                ah[i][q] = (short)hb;
                al[i][q] = (short)f2bf(x[q] - bf2f(hb));
            }
        }

        #pragma unroll
        for (int j = 0; j < 4; ++j) {
            int ef = we * 4 + j;
            int off = ((ef * 313 + kc) * 64 + l) * 8;
            short8 bh = *(const short8*)(WTh + off);
            short8 bl = *(const short8*)(WTl + off);
            #pragma unroll
            for (int i = 0; i < 2; ++i) {
                acc[i][j] = __builtin_amdgcn_mfma_f32_16x16x32_bf16(ah[i], bh, acc[i][j], 0, 0, 0);
                acc[i][j] = __builtin_amdgcn_mfma_f32_16x16x32_bf16(ah[i], bl, acc[i][j], 0, 0, 0);
                acc[i][j] = __builtin_amdgcn_mfma_f32_16x16x32_bf16(al[i], bh, acc[i][j], 0, 0, 0);
            }
        }
    }

    float* pp = part + (long long)ks * NROWS * EE;
    const int c = l & 15, r0 = g * 4;
    #pragma unroll
    for (int i = 0; i < 2; ++i) {
        #pragma unroll
        for (int j = 0; j < 4; ++j) {
            int e = (we * 4 + j) * 16 + c;
            int m = (mf0 + i) * 16 + r0;
            #pragma unroll
            for (int r = 0; r < 4; ++r)
                pp[(m + r) * EE + e] = acc[i][j][r];
        }
    }
}

// ---------------------------------------------------------------------------
// K4: out = sum over 32 splits of partial.  65536 float4 elements.
// ---------------------------------------------------------------------------
__global__ __launch_bounds__(256) void k4_reduce(
    const float* __restrict__ part, float* __restrict__ out)
{
    int idx = blockIdx.x * 256 + threadIdx.x;       // float4 index
    const float4* p = (const float4*)part;
    const int stride = NROWS * EE / 4;              // 65536
    float4 s = p[idx];
    #pragma unroll
    for (int k = 1; k < KS; k++) {
        float4 t = p[idx + k * stride];
        s.x += t.x; s.y += t.y; s.z += t.z; s.w += t.w;
    }
    ((float4*)out)[idx] = s;
}

extern "C" void kernel_launch(void* const* d_in, const int* in_sizes, int n_in,
                              void* d_out, int out_size, void* d_ws, size_t ws_size,
                              hipStream_t stream) {
    const int*   src  = (const int*)  d_in[0];
    const float* SE   = (const float*)d_in[1];
    const float* W    = (const float*)d_in[2];
    const float* edge = (const float*)d_in[3];
    const int*   rel  = (const int*)  d_in[4];
    float* out  = (float*)d_out;

    float* base = (float*)d_ws;                      // 2048*10000 f32 = 78.1 MiB
    float* part = base + (long long)NROWS * VV;      // 32*2048*128 f32 = 32 MiB
    u16* SEh = (u16*)(part + (long long)KS * NROWS * EE);
    u16* SEl = SEh + 262144;                         // 2048*128
    u16* Wh  = SEl + 262144;
    u16* Wl  = Wh  + 1280000;                        // 10000*128
    u16* WTh = Wl  + 1280000;
    u16* WTl = WTh + 1282048;                        // 8*313*512 (k-padded)
    unsigned char* rb4 = (unsigned char*)(WTl + 1282048);   // 2048*5120 = 10.5 MB
    float* cG = (float*)(rb4 + (long long)NROWS * RBSTRIDE); // 2048*10 f32

    k0_prep<<<dim3(1379), 256, 0, stream>>>(SE, W, SEh, SEl, Wh, Wl, WTh, WTl);
    k1_mfma<<<dim3(32, 79), 256, 0, stream>>>(SEh, SEl, Wh, Wl, base);
    k2_stats<<<dim3(NROWS), 256, 0, stream>>>(src, edge, rel, base, rb4, cG);
    k3_mfma<<<dim3(32, KS), 256, 0, stream>>>(base, rb4, cG, WTh, WTl, part);
    k4_reduce<<<dim3(256), 256, 0, stream>>>(part, out);
}